// Round 1
// baseline (1025.885 us; speedup 1.0000x reference)
//
#include <hip/hip_runtime.h>

#define NTOK 32768
#define NE   2048
#define EDIM 128
#define NQ   4

#define TOKT 64   // tokens per block
#define CODT 64   // codes per tile
#define DCH  64   // D-chunk staged in LDS for B

// ---------------------------------------------------------------------------
// Kernel A: per-code squared norms for all 4 levels + zero the loss accum.
// grid = (NQ*NE)/256 = 32 blocks, 256 threads: one code row per thread.
// ---------------------------------------------------------------------------
__global__ __launch_bounds__(256) void cnorm_init_kernel(
    const float* __restrict__ cb, float* __restrict__ cnorm,
    float* __restrict__ loss_accum)
{
    const int code = blockIdx.x * 256 + threadIdx.x;   // 0 .. NQ*NE-1
    if (code == 0) *loss_accum = 0.0f;
    const float4* row = (const float4*)(cb + (size_t)code * EDIM);
    float s = 0.0f;
#pragma unroll
    for (int j = 0; j < EDIM / 4; ++j) {
        float4 v = row[j];
        s += v.x * v.x; s += v.y * v.y; s += v.z * v.z; s += v.w * v.w;
    }
    cnorm[code] = s;
}

// ---------------------------------------------------------------------------
// One VQ level: distances + argmin + gather + straight-through update.
// grid = NTOK/TOKT = 512 blocks, 256 threads.
// ---------------------------------------------------------------------------
__global__ __launch_bounds__(256) void vq_level_kernel(
    const float* __restrict__ rin,     // residual in [NTOK][EDIM]
    const float* __restrict__ cb,      // this level's codebook [NE][EDIM]
    const float* __restrict__ cnorm,   // this level's [NE]
    float* __restrict__ rout,          // residual out [NTOK][EDIM]
    float* __restrict__ xq,            // accumulated quantized output
    float* __restrict__ idx_out,       // float indices, stride NQ per token
    float* __restrict__ loss_accum,
    int level, int first)
{
    __shared__ float A[EDIM][TOKT];        // 32 KB residual tile (transposed)
    __shared__ float B[DCH][CODT];         // 16 KB code chunk (transposed)
    __shared__ float rnorm_s[TOKT];
    __shared__ float part_s[4][TOKT];
    __shared__ float red_d[TOKT][16];
    __shared__ int   red_i[TOKT][16];
    __shared__ int   idx_s[TOKT];
    __shared__ float lsum[256];

    const int t    = threadIdx.x;
    const int tok0 = blockIdx.x * TOKT;

    // ---- stage residual tile (transposed) + row norms ----
    {
        const int tok = t & 63;
        const int dg  = t >> 6;            // 0..3, 32 dims each
        float s = 0.0f;
#pragma unroll
        for (int j = 0; j < 8; ++j) {
            const int d0 = dg * 32 + j * 4;
            float4 v = *(const float4*)(rin + (size_t)(tok0 + tok) * EDIM + d0);
            A[d0 + 0][tok] = v.x; A[d0 + 1][tok] = v.y;
            A[d0 + 2][tok] = v.z; A[d0 + 3][tok] = v.w;
            s += v.x * v.x; s += v.y * v.y; s += v.z * v.z; s += v.w * v.w;
        }
        part_s[dg][tok] = s;
    }
    __syncthreads();
    if (t < TOKT)
        rnorm_s[t] = ((part_s[0][t] + part_s[1][t]) + part_s[2][t]) + part_s[3][t];
    // visibility of rnorm_s is guaranteed by the barrier after the first B load

    const int tx = t & 15;    // token group (4 tokens)
    const int ty = t >> 4;    // code group  (4 codes)

    float best_d[4] = {3.402823466e38f, 3.402823466e38f,
                       3.402823466e38f, 3.402823466e38f};
    int   best_i[4] = {0, 0, 0, 0};

    for (int ct = 0; ct < NE / CODT; ++ct) {
        const int c0 = ct * CODT;
        float acc[4][4] = {{0.0f, 0.0f, 0.0f, 0.0f},
                           {0.0f, 0.0f, 0.0f, 0.0f},
                           {0.0f, 0.0f, 0.0f, 0.0f},
                           {0.0f, 0.0f, 0.0f, 0.0f}};
#pragma unroll
        for (int dc = 0; dc < EDIM / DCH; ++dc) {
            // stage B chunk [DCH][CODT] transposed
            {
                const int code = t & 63;
                const int dg   = t >> 6;    // 0..3, 16 dims each
#pragma unroll
                for (int j = 0; j < 4; ++j) {
                    const int dl = dg * 16 + j * 4;
                    float4 v = *(const float4*)(cb + (size_t)(c0 + code) * EDIM
                                                + dc * DCH + dl);
                    B[dl + 0][code] = v.x; B[dl + 1][code] = v.y;
                    B[dl + 2][code] = v.z; B[dl + 3][code] = v.w;
                }
            }
            __syncthreads();
#pragma unroll 4
            for (int d = 0; d < DCH; ++d) {
                const float4 a4 = *(const float4*)(&A[dc * DCH + d][tx * 4]);
                const float4 b4 = *(const float4*)(&B[d][ty * 4]);
                acc[0][0] += a4.x * b4.x; acc[0][1] += a4.x * b4.y;
                acc[0][2] += a4.x * b4.z; acc[0][3] += a4.x * b4.w;
                acc[1][0] += a4.y * b4.x; acc[1][1] += a4.y * b4.y;
                acc[1][2] += a4.y * b4.z; acc[1][3] += a4.y * b4.w;
                acc[2][0] += a4.z * b4.x; acc[2][1] += a4.z * b4.y;
                acc[2][2] += a4.z * b4.z; acc[2][3] += a4.z * b4.w;
                acc[3][0] += a4.w * b4.x; acc[3][1] += a4.w * b4.y;
                acc[3][2] += a4.w * b4.z; acc[3][3] += a4.w * b4.w;
            }
            __syncthreads();
        }
        // ---- argmin update (registers only; safe past the barrier) ----
        const float4 cn4 = *(const float4*)(cnorm + c0 + ty * 4);
        const float cnv[4] = {cn4.x, cn4.y, cn4.z, cn4.w};
#pragma unroll
        for (int i = 0; i < 4; ++i) {
            const float rn = rnorm_s[tx * 4 + i];
#pragma unroll
            for (int j = 0; j < 4; ++j) {
                // same evaluation order as reference: (||r||^2 - 2 r.c) + ||c||^2
                const float dist = (rn - 2.0f * acc[i][j]) + cnv[j];
                if (dist < best_d[i]) {          // strict <  -> lowest index on ties
                    best_d[i] = dist;
                    best_i[i] = c0 + ty * 4 + j;
                }
            }
        }
    }

    // ---- cross-thread argmin reduce (16 candidates per token) ----
#pragma unroll
    for (int i = 0; i < 4; ++i) {
        red_d[tx * 4 + i][ty] = best_d[i];
        red_i[tx * 4 + i][ty] = best_i[i];
    }
    __syncthreads();
    if (t < TOKT) {
        float bd = red_d[t][0];
        int   bi = red_i[t][0];
#pragma unroll
        for (int y = 1; y < 16; ++y) {
            const float dd = red_d[t][y];
            const int   ii = red_i[t][y];
            if (dd < bd || (dd == bd && ii < bi)) { bd = dd; bi = ii; }
        }
        idx_s[t] = bi;
        idx_out[(size_t)(tok0 + t) * NQ + level] = (float)bi;
    }
    __syncthreads();

    // ---- epilogue: gather + straight-through update + loss partial ----
    {
        const int tok = t >> 2;      // 0..63
        const int dq  = t & 3;       // 4 threads per token, 32 dims each
        const int gi  = idx_s[tok];
        const float* qrow = cb + (size_t)gi * EDIM;
        float lp = 0.0f;
#pragma unroll
        for (int k = 0; k < 8; ++k) {
            const int d0 = k * 16 + dq * 4;
            const float4 q = *(const float4*)(qrow + d0);
            float4 r;
            r.x = A[d0 + 0][tok]; r.y = A[d0 + 1][tok];
            r.z = A[d0 + 2][tok]; r.w = A[d0 + 3][tok];
            // replicate reference rounding exactly:
            // t = q - r; q_st = r + t; r_next = r - q_st; x_q += q_st
            float4 tq, qst, rn;
            tq.x = q.x - r.x; tq.y = q.y - r.y; tq.z = q.z - r.z; tq.w = q.w - r.w;
            qst.x = r.x + tq.x; qst.y = r.y + tq.y;
            qst.z = r.z + tq.z; qst.w = r.w + tq.w;
            rn.x = r.x - qst.x; rn.y = r.y - qst.y;
            rn.z = r.z - qst.z; rn.w = r.w - qst.w;
            const size_t go = (size_t)(tok0 + tok) * EDIM + d0;
            *(float4*)(rout + go) = rn;
            if (first) {
                *(float4*)(xq + go) = qst;
            } else {
                float4 o = *(const float4*)(xq + go);
                o.x += qst.x; o.y += qst.y; o.z += qst.z; o.w += qst.w;
                *(float4*)(xq + go) = o;
            }
            lp += tq.x * tq.x; lp += tq.y * tq.y;
            lp += tq.z * tq.z; lp += tq.w * tq.w;
        }
        lsum[t] = lp;
    }
    __syncthreads();
#pragma unroll
    for (int s2 = 128; s2 > 0; s2 >>= 1) {
        if (t < s2) lsum[t] += lsum[t + s2];
        __syncthreads();
    }
    if (t == 0) atomicAdd(loss_accum, lsum[0]);
}

// ---------------------------------------------------------------------------
// mean_loss = (1+beta) * sum((q-r)^2) / (NQ * NTOK * EDIM)
// ---------------------------------------------------------------------------
__global__ void finalize_kernel(const float* __restrict__ loss_accum,
                                float* __restrict__ out_loss)
{
    *out_loss = *loss_accum * (1.25f / (4.0f * (float)NTOK * (float)EDIM));
}

extern "C" void kernel_launch(void* const* d_in, const int* in_sizes, int n_in,
                              void* d_out, int out_size, void* d_ws, size_t ws_size,
                              hipStream_t stream)
{
    const float* x  = (const float*)d_in[0];   // [NTOK][EDIM]
    const float* cb = (const float*)d_in[1];   // [NQ][NE][EDIM]
    // d_in[2] = use_freq (unused, always 0)

    float* out      = (float*)d_out;
    float* xq       = out;                                  // [NTOK*EDIM]
    float* out_loss = out + (size_t)NTOK * EDIM;            // [1]
    float* idx_out  = out + (size_t)NTOK * EDIM + 1;        // [NTOK*NQ] as float

    float* ws         = (float*)d_ws;
    float* cnorm      = ws;                    // NQ*NE = 8192 floats
    float* loss_accum = ws + 8192;             // 1 float
    float* r0         = ws + 8448;             // 16B aligned; NTOK*EDIM floats
    float* r1         = r0 + (size_t)NTOK * EDIM;

    cnorm_init_kernel<<<(NQ * NE) / 256, 256, 0, stream>>>(cb, cnorm, loss_accum);

    const float* rin = x;
    float* rbufs[2] = {r0, r1};
    for (int l = 0; l < NQ; ++l) {
        float* rout = rbufs[l & 1];
        vq_level_kernel<<<NTOK / TOKT, 256, 0, stream>>>(
            rin, cb + (size_t)l * NE * EDIM, cnorm + l * NE,
            rout, xq, idx_out, loss_accum, l, (l == 0) ? 1 : 0);
        rin = rout;
    }
    finalize_kernel<<<1, 1, 0, stream>>>(loss_accum, out_loss);
}